// Round 15
// baseline (754.434 us; speedup 1.0000x reference)
//
#include <hip/hip_runtime.h>
#include <math.h>

#define NN 64
#define CC 160
#define LL 4096
#define DD 160
#define MM 6
#define NCH 64      // chunks per image; chunk = 64 tokens = one block
#define XSTR 68     // xb row stride in tokens (136B => 17-dword pairs: b64 conflict-free)
#define PSPL 8      // p-split factor for the partial reduction

#if defined(__has_builtin)
#if __has_builtin(__builtin_amdgcn_fdot2_f32_bf16)
#define HAVE_DOT2 1
#endif
#endif

__device__ __forceinline__ unsigned short f2bf(float f) {
  union { float f; unsigned int i; } v; v.f = f;
  unsigned int r = v.i + 0x7fffu + ((v.i >> 16) & 1u);
  return (unsigned short)(r >> 16);
}
__device__ __forceinline__ float u2f_lo(unsigned int w) {
  union { unsigned int i; float f; } v; v.i = w << 16; return v.f;
}
__device__ __forceinline__ float u2f_hi(unsigned int w) {
  union { unsigned int i; float f; } v; v.i = w & 0xffff0000u; return v.f;
}

#if HAVE_DOT2
typedef __bf16 v2bf __attribute__((ext_vector_type(2)));
__device__ __forceinline__ float dot2bf(unsigned int a, unsigned int b, float c) {
  union { unsigned int u; v2bf v; } ua, ub;
  ua.u = a; ub.u = b;
  return __builtin_amdgcn_fdot2_f32_bf16(ua.v, ub.v, c, false);
}
#else
__device__ __forceinline__ float dot2bf(unsigned int a, unsigned int b, float c) {
  return fmaf(u2f_hi(a), u2f_hi(b), fmaf(u2f_lo(a), u2f_lo(b), c));
}
#endif

// ---------------- k_init: scal = (d^-0.5 / tau); Wkq1 = scal * Wk @ q1^T ----------------
__global__ __launch_bounds__(256) void k_init(
    const float* log_tau, const float* slots_init, const float* q_g, const float* q_b,
    const float* Wq, const float* Wk, float* Wkq1, float* scal) {
  __shared__ float ln[MM * DD];
  __shared__ float qv[MM * DD];
  __shared__ float mu_s[MM], rs_s[MM];
  int tid = threadIdx.x;
  float x = log_tau[0];
  float sp = (x > 20.f) ? x : log1pf(expf(x));
  float scv = (1.0f / sqrtf((float)DD)) / (sp + 0.5f);
  if (blockIdx.x == 0 && tid == 0) scal[0] = scv;
  if (tid < MM) {
    float s = 0.f, ss = 0.f;
    for (int i = 0; i < DD; i++) { float v = slots_init[tid * DD + i]; s += v; ss += v * v; }
    float mu = s / DD, var = ss / DD - mu * mu;
    mu_s[tid] = mu; rs_s[tid] = rsqrtf(var + 1e-5f);
  }
  __syncthreads();
  for (int o = tid; o < MM * DD; o += 256) {
    int m = o / DD, d = o % DD;
    ln[o] = (slots_init[o] - mu_s[m]) * rs_s[m] * q_g[d] + q_b[d];
  }
  __syncthreads();
  for (int o = tid; o < MM * DD; o += 256) {
    int m = o / DD, d = o % DD;
    float acc = 0.f;
#pragma unroll 8
    for (int i = 0; i < DD; i++) acc += ln[m * DD + i] * Wq[i * DD + d];
    qv[o] = acc;
  }
  __syncthreads();
  for (int o = tid; o < 60; o += 256) {
    int c = blockIdx.x * 10 + o / 6, m = o % 6;
    float acc = 0.f;
#pragma unroll 8
    for (int d = 0; d < DD; d++) acc += Wk[c * DD + d] * qv[m * DD + d];
    Wkq1[c * 6 + m] = scv * acc;
  }
}

// ---------------- k_init2: P1 = g .* Wkq1; ab = [alpha | beta] ----------------
__global__ __launch_bounds__(256) void k_init2(
    const float* Wkq1, const float* kv_g, const float* kv_b, float* P1, float* ab) {
  int tid = threadIdx.x;
  for (int o = tid; o < DD * 6; o += 256) {
    int c = o / 6;
    P1[o] = kv_g[c] * Wkq1[o];
  }
  if (tid < 192) {
    int grp = tid >> 4;
    int l = tid & 15;
    int m = grp % 6;
    const float* coef = (grp < 6) ? kv_g : kv_b;
    float s = 0.f;
#pragma unroll
    for (int i = 0; i < 10; i++) {
      int c = l + i * 16;
      s += coef[c] * Wkq1[c * 6 + m];
    }
    s += __shfl_xor(s, 1); s += __shfl_xor(s, 2);
    s += __shfl_xor(s, 4); s += __shfl_xor(s, 8);
    if (l == 0) ab[grp] = s;
  }
}

// ---------------- k_pass: one 64-token tile/block; dot2 phase 2; wave-role phase 1 ----------------
template <bool ITER2>
__global__ __launch_bounds__(256) void k_pass(
    const float* __restrict__ feat, const float* __restrict__ Pg,
    const float* __restrict__ abg, float* __restrict__ Apart,
    float* __restrict__ SWpart, float* __restrict__ attn_out) {
  int b = blockIdx.x;
  int n = b >> 6, ch = b & 63;
  int tid = threadIdx.x;
  int lane = tid & 63, g = tid >> 6;
  int cg = lane >> 4, tl = lane & 15;

  __shared__ __align__(16) unsigned short xb[160 * XSTR];
  __shared__ __align__(8) float part[4][16][4][10];
  __shared__ __align__(16) unsigned int w2_s[32][8];
  __shared__ __align__(16) float P_s[160][8];

  const float* wsrc = ITER2 ? (Pg + (size_t)n * DD * 6) : Pg;
  for (int o = tid; o < DD * 6; o += 256) P_s[o / 6][o % 6] = wsrc[o];
  const float* absrc = ITER2 ? (abg + n * 12) : abg;
  float alpha[6], beta[6];
#pragma unroll
  for (int m = 0; m < 6; m++) { alpha[m] = absrc[m]; beta[m] = absrc[6 + m]; }
  __syncthreads();

  const float* fb = feat + ((size_t)(n * CC + g * 40 + cg)) * LL + ch * 64 + 4 * tl;
  float s4[4] = {0, 0, 0, 0}, ss4[4] = {0, 0, 0, 0};
  float lgr[6][4];
#pragma unroll
  for (int m = 0; m < 6; m++) { lgr[m][0] = 0.f; lgr[m][1] = 0.f; lgr[m][2] = 0.f; lgr[m][3] = 0.f; }
#pragma unroll
  for (int r = 0; r < 10; r++) {
    int c = g * 40 + r * 4 + cg;
    float4 xv = *(const float4*)(fb + (size_t)(r * 4) * LL);
    float4 p03 = *(const float4*)&P_s[c][0];
    float2 p45 = *(const float2*)&P_s[c][4];
    float xs[4] = {xv.x, xv.y, xv.z, xv.w};
#pragma unroll
    for (int j = 0; j < 4; j++) {
      float x = xs[j];
      s4[j] += x; ss4[j] = fmaf(x, x, ss4[j]);
      lgr[0][j] = fmaf(x, p03.x, lgr[0][j]); lgr[1][j] = fmaf(x, p03.y, lgr[1][j]);
      lgr[2][j] = fmaf(x, p03.z, lgr[2][j]); lgr[3][j] = fmaf(x, p03.w, lgr[3][j]);
      lgr[4][j] = fmaf(x, p45.x, lgr[4][j]); lgr[5][j] = fmaf(x, p45.y, lgr[5][j]);
    }
    uint2 pk;
    pk.x = (unsigned int)f2bf(xv.x) | ((unsigned int)f2bf(xv.y) << 16);
    pk.y = (unsigned int)f2bf(xv.z) | ((unsigned int)f2bf(xv.w) << 16);
    *(uint2*)&xb[c * XSTR + 4 * tl] = pk;
  }
#pragma unroll
  for (int j = 0; j < 4; j++) {
    s4[j] += __shfl_xor(s4[j], 16);  s4[j] += __shfl_xor(s4[j], 32);
    ss4[j] += __shfl_xor(ss4[j], 16); ss4[j] += __shfl_xor(ss4[j], 32);
#pragma unroll
    for (int m = 0; m < 6; m++) {
      lgr[m][j] += __shfl_xor(lgr[m][j], 16);
      lgr[m][j] += __shfl_xor(lgr[m][j], 32);
    }
  }
  if (cg == 0) {
#pragma unroll
    for (int j = 0; j < 4; j++) {
      float* pp = &part[g][tl][j][0];
      *(float2*)&pp[0] = make_float2(s4[j], ss4[j]);
      *(float2*)&pp[2] = make_float2(lgr[0][j], lgr[1][j]);
      *(float2*)&pp[4] = make_float2(lgr[2][j], lgr[3][j]);
      *(float2*)&pp[6] = make_float2(lgr[4][j], lgr[5][j]);
    }
  }
  __syncthreads();

  {
    int tg = lane >> 2, tj = lane & 3;
    float S = 0.f, SS = 0.f, L[6] = {0, 0, 0, 0, 0, 0};
#pragma unroll
    for (int g2 = 0; g2 < 4; g2++) {
      const float* pp = &part[g2][tg][tj][0];
      float2 a = *(const float2*)&pp[0];
      float2 b2_ = *(const float2*)&pp[2];
      float2 c2 = *(const float2*)&pp[4];
      float2 d2 = *(const float2*)&pp[6];
      S += a.x; SS += a.y;
      L[0] += b2_.x; L[1] += b2_.y; L[2] += c2.x; L[3] += c2.y; L[4] += d2.x; L[5] += d2.y;
    }
    float mu = S * (1.0f / CC);
    float var = SS * (1.0f / CC) - mu * mu;
    float rs = rsqrtf(var + 1e-5f);
    float lg[6];
#pragma unroll
    for (int m = 0; m < 6; m++) lg[m] = rs * L[m] - rs * mu * alpha[m] + beta[m];
    float mx = lg[0];
#pragma unroll
    for (int m = 1; m < 6; m++) mx = fmaxf(mx, lg[m]);
    float e[6], sum = 0.f;
#pragma unroll
    for (int m = 0; m < 6; m++) { e[m] = __expf(lg[m] - mx); sum += e[m]; }
    float inv = 1.0f / sum;
    float att[6], wv[6];
#pragma unroll
    for (int m = 0; m < 6; m++) { att[m] = e[m] * inv; wv[m] = att[m] * rs; }

    if (g == 0) {
      float wo[6];
#pragma unroll
      for (int m = 0; m < 6; m++) wo[m] = __shfl_xor(wv[m], 1);
      if (!(lane & 1)) {
        int tp = lane >> 1;
        unsigned int pk[6];
#pragma unroll
        for (int m = 0; m < 6; m++) pk[m] = (unsigned int)f2bf(wv[m]) | ((unsigned int)f2bf(wo[m]) << 16);
        *(uint4*)&w2_s[tp][0] = make_uint4(pk[0], pk[1], pk[2], pk[3]);
        *(uint2*)&w2_s[tp][4] = make_uint2(pk[4], pk[5]);
      }
    } else if (g == 1) {
      if (ITER2) {
        size_t ob = ((size_t)(n * MM)) * LL + ch * 64 + lane;
#pragma unroll
        for (int m = 0; m < 6; m++) attn_out[ob + (size_t)m * LL] = att[m];
      }
    } else if (g == 2) {
#pragma unroll
      for (int m = 0; m < 6; m++) {
        float v = att[m];
        v += __shfl_xor(v, 1);  v += __shfl_xor(v, 2);  v += __shfl_xor(v, 4);
        v += __shfl_xor(v, 8);  v += __shfl_xor(v, 16); v += __shfl_xor(v, 32);
        if (lane == 0) SWpart[b * 12 + m] = v;
      }
    } else {
#pragma unroll
      for (int m = 0; m < 6; m++) {
        float v = wv[m] * mu;
        v += __shfl_xor(v, 1);  v += __shfl_xor(v, 2);  v += __shfl_xor(v, 4);
        v += __shfl_xor(v, 8);  v += __shfl_xor(v, 16); v += __shfl_xor(v, 32);
        if (lane == 0) SWpart[b * 12 + 6 + m] = v;
      }
    }
  }
  __syncthreads();

  if (tid < DD) {
    float A0 = 0.f, A1 = 0.f, A2 = 0.f, A3 = 0.f, A4 = 0.f, A5 = 0.f;
    const unsigned short* xr = &xb[tid * XSTR];
#pragma unroll
    for (int k = 0; k < 16; k++) {
      uint2 xw = *(const uint2*)(xr + 4 * k);
      uint4 wa0 = *(const uint4*)&w2_s[2 * k][0];
      uint2 wb0 = *(const uint2*)&w2_s[2 * k][4];
      uint4 wa1 = *(const uint4*)&w2_s[2 * k + 1][0];
      uint2 wb1 = *(const uint2*)&w2_s[2 * k + 1][4];
      A0 = dot2bf(wa0.x, xw.x, A0); A1 = dot2bf(wa0.y, xw.x, A1);
      A2 = dot2bf(wa0.z, xw.x, A2); A3 = dot2bf(wa0.w, xw.x, A3);
      A4 = dot2bf(wb0.x, xw.x, A4); A5 = dot2bf(wb0.y, xw.x, A5);
      A0 = dot2bf(wa1.x, xw.y, A0); A1 = dot2bf(wa1.y, xw.y, A1);
      A2 = dot2bf(wa1.z, xw.y, A2); A3 = dot2bf(wa1.w, xw.y, A3);
      A4 = dot2bf(wb1.x, xw.y, A4); A5 = dot2bf(wb1.y, xw.y, A5);
    }
    float Aacc[6] = {A0, A1, A2, A3, A4, A5};
#pragma unroll
    for (int m = 0; m < 6; m++) Apart[((size_t)b * 6 + m) * DD + tid] = Aacc[m];
  }
}

// ---------------- k_abl<PH>: instrumentation clone of k_pass, x4 repeat ----------------
// PH bit1 (=2): logit FMAs in phase 0.  bit2 (=4): LDS part + barriers + softmax + pack.
// bit3 (=8): phase 2 dot2 + Apart writes.  Loads+stats+xb-pack always on.
template <int PH>
__global__ __launch_bounds__(256) void k_abl(
    const float* __restrict__ feat, const float* __restrict__ Pg,
    const float* __restrict__ abg, float* __restrict__ sA, float* __restrict__ sSW) {
  int b = blockIdx.x;
  int n = b >> 6, ch = b & 63;
  int tid = threadIdx.x;
  int lane = tid & 63, g = tid >> 6;
  int cg = lane >> 4, tl = lane & 15;

  __shared__ __align__(16) unsigned short xb[160 * XSTR];
  __shared__ __align__(8) float part[4][16][4][10];
  __shared__ __align__(16) unsigned int w2_s[32][8];
  __shared__ __align__(16) float P_s[160][8];

  for (int o = tid; o < DD * 6; o += 256) P_s[o / 6][o % 6] = Pg[o];
  float alpha[6], beta[6];
#pragma unroll
  for (int m = 0; m < 6; m++) { alpha[m] = abg[m]; beta[m] = abg[6 + m]; }
  __syncthreads();

  float keep = 0.f;
#pragma unroll 1
  for (int rep = 0; rep < 4; rep++) {
    int tok0 = ((ch + rep) & 63) * 64;   // shift window per rep: defeats load re-use
    const float* fb = feat + ((size_t)(n * CC + g * 40 + cg)) * LL + tok0 + 4 * tl;
    float s4[4] = {0, 0, 0, 0}, ss4[4] = {0, 0, 0, 0};
    float lgr[6][4];
#pragma unroll
    for (int m = 0; m < 6; m++) { lgr[m][0] = 0.f; lgr[m][1] = 0.f; lgr[m][2] = 0.f; lgr[m][3] = 0.f; }
#pragma unroll
    for (int r = 0; r < 10; r++) {
      int c = g * 40 + r * 4 + cg;
      float4 xv = *(const float4*)(fb + (size_t)(r * 4) * LL);
      float xs[4] = {xv.x, xv.y, xv.z, xv.w};
      if (PH & 2) {
        float4 p03 = *(const float4*)&P_s[c][0];
        float2 p45 = *(const float2*)&P_s[c][4];
#pragma unroll
        for (int j = 0; j < 4; j++) {
          float x = xs[j];
          s4[j] += x; ss4[j] = fmaf(x, x, ss4[j]);
          lgr[0][j] = fmaf(x, p03.x, lgr[0][j]); lgr[1][j] = fmaf(x, p03.y, lgr[1][j]);
          lgr[2][j] = fmaf(x, p03.z, lgr[2][j]); lgr[3][j] = fmaf(x, p03.w, lgr[3][j]);
          lgr[4][j] = fmaf(x, p45.x, lgr[4][j]); lgr[5][j] = fmaf(x, p45.y, lgr[5][j]);
        }
      } else {
#pragma unroll
        for (int j = 0; j < 4; j++) {
          float x = xs[j];
          s4[j] += x; ss4[j] = fmaf(x, x, ss4[j]);
        }
      }
      uint2 pk;
      pk.x = (unsigned int)f2bf(xv.x) | ((unsigned int)f2bf(xv.y) << 16);
      pk.y = (unsigned int)f2bf(xv.z) | ((unsigned int)f2bf(xv.w) << 16);
      *(uint2*)&xb[c * XSTR + 4 * tl] = pk;
    }
    if (PH & 4) {
#pragma unroll
      for (int j = 0; j < 4; j++) {
        s4[j] += __shfl_xor(s4[j], 16);  s4[j] += __shfl_xor(s4[j], 32);
        ss4[j] += __shfl_xor(ss4[j], 16); ss4[j] += __shfl_xor(ss4[j], 32);
#pragma unroll
        for (int m = 0; m < 6; m++) {
          lgr[m][j] += __shfl_xor(lgr[m][j], 16);
          lgr[m][j] += __shfl_xor(lgr[m][j], 32);
        }
      }
      if (cg == 0) {
#pragma unroll
        for (int j = 0; j < 4; j++) {
          float* pp = &part[g][tl][j][0];
          *(float2*)&pp[0] = make_float2(s4[j], ss4[j]);
          *(float2*)&pp[2] = make_float2(lgr[0][j], lgr[1][j]);
          *(float2*)&pp[4] = make_float2(lgr[2][j], lgr[3][j]);
          *(float2*)&pp[6] = make_float2(lgr[4][j], lgr[5][j]);
        }
      }
      __syncthreads();
      {
        int tg = lane >> 2, tj = lane & 3;
        float S = 0.f, SS = 0.f, L[6] = {0, 0, 0, 0, 0, 0};
#pragma unroll
        for (int g2 = 0; g2 < 4; g2++) {
          const float* pp = &part[g2][tg][tj][0];
          float2 a = *(const float2*)&pp[0];
          float2 b2_ = *(const float2*)&pp[2];
          float2 c2 = *(const float2*)&pp[4];
          float2 d2 = *(const float2*)&pp[6];
          S += a.x; SS += a.y;
          L[0] += b2_.x; L[1] += b2_.y; L[2] += c2.x; L[3] += c2.y; L[4] += d2.x; L[5] += d2.y;
        }
        float mu = S * (1.0f / CC);
        float var = SS * (1.0f / CC) - mu * mu;
        float rs = rsqrtf(var + 1e-5f);
        float lg[6];
#pragma unroll
        for (int m = 0; m < 6; m++) lg[m] = rs * L[m] - rs * mu * alpha[m] + beta[m];
        float mx = lg[0];
#pragma unroll
        for (int m = 1; m < 6; m++) mx = fmaxf(mx, lg[m]);
        float e[6], sum = 0.f;
#pragma unroll
        for (int m = 0; m < 6; m++) { e[m] = __expf(lg[m] - mx); sum += e[m]; }
        float inv = 1.0f / sum;
        float att[6], wv[6];
#pragma unroll
        for (int m = 0; m < 6; m++) { att[m] = e[m] * inv; wv[m] = att[m] * rs; }
        if (g == 0) {
          float wo[6];
#pragma unroll
          for (int m = 0; m < 6; m++) wo[m] = __shfl_xor(wv[m], 1);
          if (!(lane & 1)) {
            int tp = lane >> 1;
            unsigned int pk[6];
#pragma unroll
            for (int m = 0; m < 6; m++) pk[m] = (unsigned int)f2bf(wv[m]) | ((unsigned int)f2bf(wo[m]) << 16);
            *(uint4*)&w2_s[tp][0] = make_uint4(pk[0], pk[1], pk[2], pk[3]);
            *(uint2*)&w2_s[tp][4] = make_uint2(pk[4], pk[5]);
          }
        } else if (g == 1) {
          float k2 = att[0] + att[1] + att[2] + att[3] + att[4] + att[5];
          asm volatile("" :: "v"(k2));   // keep wave-1 softmax alive (k_pass<true> writes attn here)
        } else if (g == 2) {
#pragma unroll
          for (int m = 0; m < 6; m++) {
            float v = att[m];
            v += __shfl_xor(v, 1);  v += __shfl_xor(v, 2);  v += __shfl_xor(v, 4);
            v += __shfl_xor(v, 8);  v += __shfl_xor(v, 16); v += __shfl_xor(v, 32);
            if (lane == 0) sSW[b * 12 + m] = v;
          }
        } else {
#pragma unroll
          for (int m = 0; m < 6; m++) {
            float v = wv[m] * mu;
            v += __shfl_xor(v, 1);  v += __shfl_xor(v, 2);  v += __shfl_xor(v, 4);
            v += __shfl_xor(v, 8);  v += __shfl_xor(v, 16); v += __shfl_xor(v, 32);
            if (lane == 0) sSW[b * 12 + 6 + m] = v;
          }
        }
      }
      __syncthreads();
    } else {
      keep += s4[0] + s4[1] + s4[2] + s4[3] + ss4[0] + ss4[1] + ss4[2] + ss4[3];
      if (PH & 2) {
#pragma unroll
        for (int m = 0; m < 6; m++) keep += lgr[m][0] + lgr[m][1] + lgr[m][2] + lgr[m][3];
      }
      asm volatile("" :: "v"(keep));
    }
    if (PH & 8) {
      if (tid < DD) {
        float A0 = 0.f, A1 = 0.f, A2 = 0.f, A3 = 0.f, A4 = 0.f, A5 = 0.f;
        const unsigned short* xr = &xb[tid * XSTR];
#pragma unroll
        for (int k = 0; k < 16; k++) {
          uint2 xw = *(const uint2*)(xr + 4 * k);
          uint4 wa0 = *(const uint4*)&w2_s[2 * k][0];
          uint2 wb0 = *(const uint2*)&w2_s[2 * k][4];
          uint4 wa1 = *(const uint4*)&w2_s[2 * k + 1][0];
          uint2 wb1 = *(const uint2*)&w2_s[2 * k + 1][4];
          A0 = dot2bf(wa0.x, xw.x, A0); A1 = dot2bf(wa0.y, xw.x, A1);
          A2 = dot2bf(wa0.z, xw.x, A2); A3 = dot2bf(wa0.w, xw.x, A3);
          A4 = dot2bf(wb0.x, xw.x, A4); A5 = dot2bf(wb0.y, xw.x, A5);
          A0 = dot2bf(wa1.x, xw.y, A0); A1 = dot2bf(wa1.y, xw.y, A1);
          A2 = dot2bf(wa1.z, xw.y, A2); A3 = dot2bf(wa1.w, xw.y, A3);
          A4 = dot2bf(wb1.x, xw.y, A4); A5 = dot2bf(wb1.y, xw.y, A5);
        }
        float Aacc[6] = {A0, A1, A2, A3, A4, A5};
#pragma unroll
        for (int m = 0; m < 6; m++) sA[((size_t)b * 6 + m) * DD + tid] = Aacc[m];
      }
      __syncthreads();
    }
  }
  if (!(PH & 8)) {
    // keep xb stores (and w2_s pack for PH=7) alive: data-dependent LDS consumer
    __syncthreads();
    keep += (float)xb[tid] + (float)(w2_s[tid & 31][0] & 0xFFu);
    asm volatile("" :: "v"(keep));
  }
}

// ---------------- k_reduce: p-split x8. Apart[n*64][6][160] -> Ared8[n][8][6][160] ----------------
__global__ __launch_bounds__(256) void k_reduce(
    const float* __restrict__ Apart, const float* __restrict__ SWpart,
    float* __restrict__ Ared8, float* __restrict__ SWred8) {
  int b = blockIdx.x;            // n*48 + m*8 + ps
  int n = b / 48;
  int r = b % 48;
  int m = r >> 3, ps = r & 7;
  int tid = threadIdx.x;
  if (tid < DD) {
    const float* src = Apart + ((size_t)(n * NCH + ps * 8) * 6 + m) * DD + tid;
    float s0 = src[0 * 6 * DD] + src[1 * 6 * DD];
    float s1 = src[2 * 6 * DD] + src[3 * 6 * DD];
    float s2 = src[4 * 6 * DD] + src[5 * 6 * DD];
    float s3 = src[6 * 6 * DD] + src[7 * 6 * DD];
    Ared8[((size_t)(n * PSPL + ps) * 6 + m) * DD + tid] = (s0 + s1) + (s2 + s3);
  } else if (m == 0 && tid >= 192 && tid < 204) {
    int k = tid - 192;
    const float* src = SWpart + (size_t)(n * NCH + ps * 8) * 12 + k;
    float s0 = src[0 * 12] + src[1 * 12];
    float s1 = src[2 * 12] + src[3 * 12];
    float s2 = src[4 * 12] + src[5 * 12];
    float s3 = src[6 * 12] + src[7 * 12];
    SWred8[(n * PSPL + ps) * 12 + k] = (s0 + s1) + (s2 + s3);
  }
}

// ---------------- k_slot2: final 8-way sum + g/b correction, slot update, LN, MLP, next P ----------------
template <bool FIRST, bool LAST>
__global__ __launch_bounds__(512) void k_slot2(
    const float* slots_init, const float* Ared8, const float* SWred8, const float* Wv,
    const float* out_g, const float* out_b,
    const float* W1, const float* b1, const float* W2, const float* b2,
    const float* q_g, const float* q_b, const float* Wq, const float* Wk,
    const float* kv_g, const float* kv_b, const float* scal,
    float* slotbuf, float* P2, float* ab2, float* Sfin, float* out_slots) {
  int n = blockIdx.x;
  int tid = threadIdx.x;
  __shared__ float a_s[MM * DD];
  __shared__ float s1[MM * DD];
  __shared__ float h[MM * 320];
  __shared__ float sw[12];
  __shared__ float Sv[MM], mu_s[MM], rs_s[MM];

  if (tid < 12) {
    const float* src = SWred8 + (size_t)n * PSPL * 12 + tid;
    float s = 0.f;
#pragma unroll
    for (int ps = 0; ps < PSPL; ps++) s += src[ps * 12];
    sw[tid] = s;
    if (tid < 6) {
      float sc = fmaxf(s, 1e-6f);
      Sv[tid] = sc;
      if (LAST) Sfin[n * 6 + tid] = sc;
    }
  }
  __syncthreads();
  for (int o = tid; o < MM * DD; o += 512) {
    int m = o / DD, c = o % DD;
    const float* src = Ared8 + (size_t)n * PSPL * MM * DD + o;
    float ar = 0.f;
#pragma unroll
    for (int ps = 0; ps < PSPL; ps++) ar += src[ps * MM * DD];
    a_s[o] = kv_g[c] * (ar - sw[6 + m]) + kv_b[c] * sw[m];
  }
  __syncthreads();
  for (int o = tid; o < MM * DD; o += 512) {
    int m = o / DD, d = o % DD;
    float u = 0.f;
#pragma unroll 8
    for (int c = 0; c < DD; c++) u += a_s[m * DD + c] * Wv[c * DD + d];
    float prev = FIRST ? slots_init[o] : slotbuf[(size_t)n * MM * DD + o];
    s1[o] = prev + u / Sv[m];
  }
  __syncthreads();
  if (tid < 384) {
    int m = tid >> 6, l = tid & 63;
    const float* row = &s1[m * DD];
    float x0 = row[l], x1 = row[l + 64], x2 = (l < 32 ? row[l + 128] : 0.f);
    float s = x0 + x1 + x2, ss = x0 * x0 + x1 * x1 + x2 * x2;
#pragma unroll
    for (int off = 32; off >= 1; off >>= 1) { s += __shfl_xor(s, off); ss += __shfl_xor(ss, off); }
    if (l == 0) {
      float mu = s / DD, var = ss / DD - mu * mu;
      mu_s[m] = mu; rs_s[m] = rsqrtf(var + 1e-5f);
    }
  }
  __syncthreads();
  for (int o = tid; o < MM * DD; o += 512) {
    int m = o / DD, d = o % DD;
    s1[o] = (s1[o] - mu_s[m]) * rs_s[m] * out_g[d] + out_b[d];
  }
  __syncthreads();
  for (int o = tid; o < MM * 320; o += 512) {
    int m = o / 320, j = o % 320;
    float acc = b1[j];
#pragma unroll 8
    for (int d = 0; d < DD; d++) acc += s1[m * DD + d] * W1[d * 320 + j];
    h[o] = 0.5f * acc * (1.0f + erff(acc * 0.70710678118f));
  }
  __syncthreads();
  for (int o = tid; o < MM * DD; o += 512) {
    int m = o / DD, d = o % DD;
    float acc = b2[d];
#pragma unroll 8
    for (int j = 0; j < 320; j++) acc += h[m * 320 + j] * W2[j * DD + d];
    float val = s1[o] + acc;
    a_s[o] = val;
    if (LAST) out_slots[(size_t)n * MM * DD + o] = val;
    else slotbuf[(size_t)n * MM * DD + o] = val;
  }
  if (!LAST) {
    __syncthreads();
    if (tid < 384) {
      int m = tid >> 6, l = tid & 63;
      const float* row = &a_s[m * DD];
      float x0 = row[l], x1 = row[l + 64], x2 = (l < 32 ? row[l + 128] : 0.f);
      float s = x0 + x1 + x2, ss = x0 * x0 + x1 * x1 + x2 * x2;
#pragma unroll
      for (int off = 32; off >= 1; off >>= 1) { s += __shfl_xor(s, off); ss += __shfl_xor(ss, off); }
      if (l == 0) {
        float mu = s / DD, var = ss / DD - mu * mu;
        mu_s[m] = mu; rs_s[m] = rsqrtf(var + 1e-5f);
      }
    }
    __syncthreads();
    for (int o = tid; o < MM * DD; o += 512) {
      int m = o / DD, d = o % DD;
      s1[o] = (a_s[o] - mu_s[m]) * rs_s[m] * q_g[d] + q_b[d];
    }
    __syncthreads();
    for (int o = tid; o < MM * DD; o += 512) {
      int m = o / DD, d = o % DD;
      float acc = 0.f;
#pragma unroll 8
      for (int i = 0; i < DD; i++) acc += s1[m * DD + i] * Wq[i * DD + d];
      h[o] = acc;
    }
    __syncthreads();
    if (tid < DD) {
      int c = tid;
      float acc[MM] = {0, 0, 0, 0, 0, 0};
#pragma unroll 4
      for (int d = 0; d < DD; d++) {
        float wk = Wk[c * DD + d];
#pragma unroll
        for (int m = 0; m < MM; m++) acc[m] += wk * h[m * DD + d];
      }
      float sc = scal[0];
      float gc = kv_g[c], bc = kv_b[c];
#pragma unroll
      for (int m = 0; m < MM; m++) {
        float wr = sc * acc[m];
        P2[(size_t)n * DD * 6 + c * 6 + m] = gc * wr;
        s1[c * 6 + m] = gc * wr;
        a_s[c * 6 + m] = bc * wr;
      }
    }
    __syncthreads();
    if (tid < 192) {
      int grp = tid >> 4;
      int l = tid & 15;
      int m = grp % 6;
      const float* src = (grp < 6) ? s1 : a_s;
      float s = 0.f;
#pragma unroll
      for (int i = 0; i < 10; i++) s += src[(l + i * 16) * 6 + m];
      s += __shfl_xor(s, 1); s += __shfl_xor(s, 2);
      s += __shfl_xor(s, 4); s += __shfl_xor(s, 8);
      if (l == 0) ab2[n * 12 + grp] = s;
    }
  }
}

// ---------------- k_norm: attn_map = attn / Sfin ----------------
__global__ __launch_bounds__(256) void k_norm(float* attn, const float* Sfin) {
  int idx = blockIdx.x * 256 + threadIdx.x;
  size_t base = (size_t)idx * 4;
  int nm = (int)(base >> 12);
  float s = Sfin[nm];
  float4 v = *(float4*)(attn + base);
  float inv = 1.0f / s;
  v.x *= inv; v.y *= inv; v.z *= inv; v.w *= inv;
  *(float4*)(attn + base) = v;
}

extern "C" void kernel_launch(void* const* d_in, const int* in_sizes, int n_in,
                              void* d_out, int out_size, void* d_ws, size_t ws_size,
                              hipStream_t stream) {
  const float* feat       = (const float*)d_in[0];
  const float* slots_init = (const float*)d_in[1];
  const float* log_tau    = (const float*)d_in[2];
  const float* kv_g       = (const float*)d_in[3];
  const float* kv_b       = (const float*)d_in[4];
  const float* Wk         = (const float*)d_in[5];
  const float* Wv         = (const float*)d_in[6];
  const float* q_g        = (const float*)d_in[7];
  const float* q_b        = (const float*)d_in[8];
  const float* Wq         = (const float*)d_in[9];
  const float* out_g      = (const float*)d_in[10];
  const float* out_b      = (const float*)d_in[11];
  const float* W1         = (const float*)d_in[12];
  const float* b1         = (const float*)d_in[13];
  const float* W2         = (const float*)d_in[14];
  const float* b2         = (const float*)d_in[15];
  float* out = (float*)d_out;
  float* out_attn = out + NN * MM * DD;

  // workspace (fp32, ~19 MB)
  float* Wkq1   = (float*)d_ws;                          // [160*6]
  float* ab     = Wkq1 + DD * 6;                         // [12] (pad 16)
  float* P1     = ab + 16;                               // [160*6]
  float* P2     = P1 + DD * 6;                           // [64][160*6]
  float* ab2    = P2 + (size_t)NN * DD * 6;              // [64][12]
  float* Apart  = ab2 + NN * 12;                         // [4096][6][160]
  float* SWpart = Apart + (size_t)NN * NCH * MM * DD;    // [4096][12]
  float* Ared8  = SWpart + (size_t)NN * NCH * 12;        // [64][8][6][160]
  float* SWred8 = Ared8 + (size_t)NN * PSPL * MM * DD;   // [64][8][12]
  float* Sfin   = SWred8 + NN * PSPL * 12;               // [64][6]
  float* scal   = Sfin + NN * MM;                        // [1] (pad 8)
  float* slotbuf = scal + 8;                             // [64][6][160]
  size_t required = (size_t)((char*)(slotbuf + NN * MM * DD) - (char*)d_ws);
  if (ws_size < required) return;

  k_init<<<16, 256, 0, stream>>>(log_tau, slots_init, q_g, q_b, Wq, Wk, Wkq1, scal);
  k_init2<<<1, 256, 0, stream>>>(Wkq1, kv_g, kv_b, P1, ab);
  k_pass<false><<<NN * NCH, 256, 0, stream>>>(feat, P1, ab, Apart, SWpart, out_attn);
  k_reduce<<<NN * MM * PSPL, 256, 0, stream>>>(Apart, SWpart, Ared8, SWred8);
  k_slot2<true, false><<<NN, 512, 0, stream>>>(slots_init, Ared8, SWred8, Wv, out_g, out_b,
                                               W1, b1, W2, b2, q_g, q_b, Wq, Wk, kv_g, kv_b, scal,
                                               slotbuf, P2, ab2, Sfin, out);
  k_pass<true><<<NN * NCH, 256, 0, stream>>>(feat, P2, ab2, Apart, SWpart, out_attn);
  k_reduce<<<NN * MM * PSPL, 256, 0, stream>>>(Apart, SWpart, Ared8, SWred8);
  k_slot2<false, true><<<NN, 512, 0, stream>>>(slots_init, Ared8, SWred8, Wv, out_g, out_b,
                                               W1, b1, W2, b2, q_g, q_b, Wq, Wk, kv_g, kv_b, scal,
                                               slotbuf, P2, ab2, Sfin, out);
  k_norm<<<(NN * MM * LL) / 1024, 256, 0, stream>>>(out_attn, Sfin);

  // ---- instrumentation: 4x-repeat phase-ablated k_pass clones (scratch = dead Apart/SWpart) ----
  k_abl<1><<<NN * NCH, 256, 0, stream>>>(feat, P1, ab, Apart, SWpart);
  k_abl<3><<<NN * NCH, 256, 0, stream>>>(feat, P1, ab, Apart, SWpart);
  k_abl<7><<<NN * NCH, 256, 0, stream>>>(feat, P1, ab, Apart, SWpart);
  k_abl<15><<<NN * NCH, 256, 0, stream>>>(feat, P1, ab, Apart, SWpart);
}

// Round 16
// 223.762 us; speedup vs baseline: 3.3716x; 3.3716x over previous
//
#include <hip/hip_runtime.h>
#include <math.h>

#define NN 64
#define CC 160
#define LL 4096
#define DD 160
#define MM 6
#define NCH 64      // chunks per image; chunk = 64 tokens = one block
#define XSTR 68     // xb row stride in tokens (136B => 17-dword pairs: b64 conflict-free)
#define PSPL 8      // p-split factor for the partial reduction

#if defined(__has_builtin)
#if __has_builtin(__builtin_amdgcn_fdot2_f32_bf16)
#define HAVE_DOT2 1
#endif
#endif

__device__ __forceinline__ unsigned short f2bf(float f) {
  union { float f; unsigned int i; } v; v.f = f;
  unsigned int r = v.i + 0x7fffu + ((v.i >> 16) & 1u);
  return (unsigned short)(r >> 16);
}
__device__ __forceinline__ float u2f_lo(unsigned int w) {
  union { unsigned int i; float f; } v; v.i = w << 16; return v.f;
}
__device__ __forceinline__ float u2f_hi(unsigned int w) {
  union { unsigned int i; float f; } v; v.i = w & 0xffff0000u; return v.f;
}

#if HAVE_DOT2
typedef __bf16 v2bf __attribute__((ext_vector_type(2)));
__device__ __forceinline__ float dot2bf(unsigned int a, unsigned int b, float c) {
  union { unsigned int u; v2bf v; } ua, ub;
  ua.u = a; ub.u = b;
  return __builtin_amdgcn_fdot2_f32_bf16(ua.v, ub.v, c, false);
}
#else
__device__ __forceinline__ float dot2bf(unsigned int a, unsigned int b, float c) {
  return fmaf(u2f_hi(a), u2f_hi(b), fmaf(u2f_lo(a), u2f_lo(b), c));
}
#endif

// ---------------- k_init: scal = (d^-0.5 / tau); Wkq1 = scal * Wk @ q1^T ----------------
__global__ __launch_bounds__(256) void k_init(
    const float* log_tau, const float* slots_init, const float* q_g, const float* q_b,
    const float* Wq, const float* Wk, float* Wkq1, float* scal) {
  __shared__ float ln[MM * DD];
  __shared__ float qv[MM * DD];
  __shared__ float mu_s[MM], rs_s[MM];
  int tid = threadIdx.x;
  float x = log_tau[0];
  float sp = (x > 20.f) ? x : log1pf(expf(x));
  float scv = (1.0f / sqrtf((float)DD)) / (sp + 0.5f);
  if (blockIdx.x == 0 && tid == 0) scal[0] = scv;
  if (tid < MM) {
    float s = 0.f, ss = 0.f;
    for (int i = 0; i < DD; i++) { float v = slots_init[tid * DD + i]; s += v; ss += v * v; }
    float mu = s / DD, var = ss / DD - mu * mu;
    mu_s[tid] = mu; rs_s[tid] = rsqrtf(var + 1e-5f);
  }
  __syncthreads();
  for (int o = tid; o < MM * DD; o += 256) {
    int m = o / DD, d = o % DD;
    ln[o] = (slots_init[o] - mu_s[m]) * rs_s[m] * q_g[d] + q_b[d];
  }
  __syncthreads();
  for (int o = tid; o < MM * DD; o += 256) {
    int m = o / DD, d = o % DD;
    float acc = 0.f;
#pragma unroll 8
    for (int i = 0; i < DD; i++) acc += ln[m * DD + i] * Wq[i * DD + d];
    qv[o] = acc;
  }
  __syncthreads();
  for (int o = tid; o < 60; o += 256) {
    int c = blockIdx.x * 10 + o / 6, m = o % 6;
    float acc = 0.f;
#pragma unroll 8
    for (int d = 0; d < DD; d++) acc += Wk[c * DD + d] * qv[m * DD + d];
    Wkq1[c * 6 + m] = scv * acc;
  }
}

// ---------------- k_init2: P1 = g .* Wkq1; ab = [alpha | beta] ----------------
__global__ __launch_bounds__(256) void k_init2(
    const float* Wkq1, const float* kv_g, const float* kv_b, float* P1, float* ab) {
  int tid = threadIdx.x;
  for (int o = tid; o < DD * 6; o += 256) {
    int c = o / 6;
    P1[o] = kv_g[c] * Wkq1[o];
  }
  if (tid < 192) {
    int grp = tid >> 4;
    int l = tid & 15;
    int m = grp % 6;
    const float* coef = (grp < 6) ? kv_g : kv_b;
    float s = 0.f;
#pragma unroll
    for (int i = 0; i < 10; i++) {
      int c = l + i * 16;
      s += coef[c] * Wkq1[c * 6 + m];
    }
    s += __shfl_xor(s, 1); s += __shfl_xor(s, 2);
    s += __shfl_xor(s, 4); s += __shfl_xor(s, 8);
    if (l == 0) ab[grp] = s;
  }
}

// ---------------- k_pass: one 64-token tile/block; dot2 phase 2; wave-role phase 1 ----------------
template <bool ITER2>
__global__ __launch_bounds__(256) void k_pass(
    const float* __restrict__ feat, const float* __restrict__ Pg,
    const float* __restrict__ abg, float* __restrict__ Apart,
    float* __restrict__ SWpart, float* __restrict__ attn_out) {
  int b = blockIdx.x;
  int n = b >> 6, ch = b & 63;
  int tid = threadIdx.x;
  int lane = tid & 63, g = tid >> 6;
  int cg = lane >> 4, tl = lane & 15;

  __shared__ __align__(16) unsigned short xb[160 * XSTR];
  __shared__ __align__(8) float part[4][16][4][10];
  __shared__ __align__(16) unsigned int w2_s[32][8];
  __shared__ __align__(16) float P_s[160][8];

  const float* wsrc = ITER2 ? (Pg + (size_t)n * DD * 6) : Pg;
  for (int o = tid; o < DD * 6; o += 256) P_s[o / 6][o % 6] = wsrc[o];
  const float* absrc = ITER2 ? (abg + n * 12) : abg;
  float alpha[6], beta[6];
#pragma unroll
  for (int m = 0; m < 6; m++) { alpha[m] = absrc[m]; beta[m] = absrc[6 + m]; }
  __syncthreads();

  const float* fb = feat + ((size_t)(n * CC + g * 40 + cg)) * LL + ch * 64 + 4 * tl;
  float s4[4] = {0, 0, 0, 0}, ss4[4] = {0, 0, 0, 0};
  float lgr[6][4];
#pragma unroll
  for (int m = 0; m < 6; m++) { lgr[m][0] = 0.f; lgr[m][1] = 0.f; lgr[m][2] = 0.f; lgr[m][3] = 0.f; }
#pragma unroll
  for (int r = 0; r < 10; r++) {
    int c = g * 40 + r * 4 + cg;
    float4 xv = *(const float4*)(fb + (size_t)(r * 4) * LL);
    float4 p03 = *(const float4*)&P_s[c][0];
    float2 p45 = *(const float2*)&P_s[c][4];
    float xs[4] = {xv.x, xv.y, xv.z, xv.w};
#pragma unroll
    for (int j = 0; j < 4; j++) {
      float x = xs[j];
      s4[j] += x; ss4[j] = fmaf(x, x, ss4[j]);
      lgr[0][j] = fmaf(x, p03.x, lgr[0][j]); lgr[1][j] = fmaf(x, p03.y, lgr[1][j]);
      lgr[2][j] = fmaf(x, p03.z, lgr[2][j]); lgr[3][j] = fmaf(x, p03.w, lgr[3][j]);
      lgr[4][j] = fmaf(x, p45.x, lgr[4][j]); lgr[5][j] = fmaf(x, p45.y, lgr[5][j]);
    }
    uint2 pk;
    pk.x = (unsigned int)f2bf(xv.x) | ((unsigned int)f2bf(xv.y) << 16);
    pk.y = (unsigned int)f2bf(xv.z) | ((unsigned int)f2bf(xv.w) << 16);
    *(uint2*)&xb[c * XSTR + 4 * tl] = pk;
  }
#pragma unroll
  for (int j = 0; j < 4; j++) {
    s4[j] += __shfl_xor(s4[j], 16);  s4[j] += __shfl_xor(s4[j], 32);
    ss4[j] += __shfl_xor(ss4[j], 16); ss4[j] += __shfl_xor(ss4[j], 32);
#pragma unroll
    for (int m = 0; m < 6; m++) {
      lgr[m][j] += __shfl_xor(lgr[m][j], 16);
      lgr[m][j] += __shfl_xor(lgr[m][j], 32);
    }
  }
  if (cg == 0) {
#pragma unroll
    for (int j = 0; j < 4; j++) {
      float* pp = &part[g][tl][j][0];
      *(float2*)&pp[0] = make_float2(s4[j], ss4[j]);
      *(float2*)&pp[2] = make_float2(lgr[0][j], lgr[1][j]);
      *(float2*)&pp[4] = make_float2(lgr[2][j], lgr[3][j]);
      *(float2*)&pp[6] = make_float2(lgr[4][j], lgr[5][j]);
    }
  }
  __syncthreads();

  {
    int tg = lane >> 2, tj = lane & 3;
    float S = 0.f, SS = 0.f, L[6] = {0, 0, 0, 0, 0, 0};
#pragma unroll
    for (int g2 = 0; g2 < 4; g2++) {
      const float* pp = &part[g2][tg][tj][0];
      float2 a = *(const float2*)&pp[0];
      float2 b2_ = *(const float2*)&pp[2];
      float2 c2 = *(const float2*)&pp[4];
      float2 d2 = *(const float2*)&pp[6];
      S += a.x; SS += a.y;
      L[0] += b2_.x; L[1] += b2_.y; L[2] += c2.x; L[3] += c2.y; L[4] += d2.x; L[5] += d2.y;
    }
    float mu = S * (1.0f / CC);
    float var = SS * (1.0f / CC) - mu * mu;
    float rs = rsqrtf(var + 1e-5f);
    float lg[6];
#pragma unroll
    for (int m = 0; m < 6; m++) lg[m] = rs * L[m] - rs * mu * alpha[m] + beta[m];
    float mx = lg[0];
#pragma unroll
    for (int m = 1; m < 6; m++) mx = fmaxf(mx, lg[m]);
    float e[6], sum = 0.f;
#pragma unroll
    for (int m = 0; m < 6; m++) { e[m] = __expf(lg[m] - mx); sum += e[m]; }
    float inv = 1.0f / sum;
    float att[6], wv[6];
#pragma unroll
    for (int m = 0; m < 6; m++) { att[m] = e[m] * inv; wv[m] = att[m] * rs; }

    if (g == 0) {
      float wo[6];
#pragma unroll
      for (int m = 0; m < 6; m++) wo[m] = __shfl_xor(wv[m], 1);
      if (!(lane & 1)) {
        int tp = lane >> 1;
        unsigned int pk[6];
#pragma unroll
        for (int m = 0; m < 6; m++) pk[m] = (unsigned int)f2bf(wv[m]) | ((unsigned int)f2bf(wo[m]) << 16);
        *(uint4*)&w2_s[tp][0] = make_uint4(pk[0], pk[1], pk[2], pk[3]);
        *(uint2*)&w2_s[tp][4] = make_uint2(pk[4], pk[5]);
      }
    } else if (g == 1) {
      if (ITER2) {
        size_t ob = ((size_t)(n * MM)) * LL + ch * 64 + lane;
#pragma unroll
        for (int m = 0; m < 6; m++) attn_out[ob + (size_t)m * LL] = att[m];
      }
    } else if (g == 2) {
#pragma unroll
      for (int m = 0; m < 6; m++) {
        float v = att[m];
        v += __shfl_xor(v, 1);  v += __shfl_xor(v, 2);  v += __shfl_xor(v, 4);
        v += __shfl_xor(v, 8);  v += __shfl_xor(v, 16); v += __shfl_xor(v, 32);
        if (lane == 0) SWpart[b * 12 + m] = v;
      }
    } else {
#pragma unroll
      for (int m = 0; m < 6; m++) {
        float v = wv[m] * mu;
        v += __shfl_xor(v, 1);  v += __shfl_xor(v, 2);  v += __shfl_xor(v, 4);
        v += __shfl_xor(v, 8);  v += __shfl_xor(v, 16); v += __shfl_xor(v, 32);
        if (lane == 0) SWpart[b * 12 + 6 + m] = v;
      }
    }
  }
  __syncthreads();

  if (tid < DD) {
    float A0 = 0.f, A1 = 0.f, A2 = 0.f, A3 = 0.f, A4 = 0.f, A5 = 0.f;
    const unsigned short* xr = &xb[tid * XSTR];
#pragma unroll
    for (int k = 0; k < 16; k++) {
      uint2 xw = *(const uint2*)(xr + 4 * k);
      uint4 wa0 = *(const uint4*)&w2_s[2 * k][0];
      uint2 wb0 = *(const uint2*)&w2_s[2 * k][4];
      uint4 wa1 = *(const uint4*)&w2_s[2 * k + 1][0];
      uint2 wb1 = *(const uint2*)&w2_s[2 * k + 1][4];
      A0 = dot2bf(wa0.x, xw.x, A0); A1 = dot2bf(wa0.y, xw.x, A1);
      A2 = dot2bf(wa0.z, xw.x, A2); A3 = dot2bf(wa0.w, xw.x, A3);
      A4 = dot2bf(wb0.x, xw.x, A4); A5 = dot2bf(wb0.y, xw.x, A5);
      A0 = dot2bf(wa1.x, xw.y, A0); A1 = dot2bf(wa1.y, xw.y, A1);
      A2 = dot2bf(wa1.z, xw.y, A2); A3 = dot2bf(wa1.w, xw.y, A3);
      A4 = dot2bf(wb1.x, xw.y, A4); A5 = dot2bf(wb1.y, xw.y, A5);
    }
    float Aacc[6] = {A0, A1, A2, A3, A4, A5};
#pragma unroll
    for (int m = 0; m < 6; m++) Apart[((size_t)b * 6 + m) * DD + tid] = Aacc[m];
  }
}

// ---------------- k_reduce: p-split x8. Apart[n*64][6][160] -> Ared8[n][8][6][160] ----------------
__global__ __launch_bounds__(256) void k_reduce(
    const float* __restrict__ Apart, const float* __restrict__ SWpart,
    float* __restrict__ Ared8, float* __restrict__ SWred8) {
  int b = blockIdx.x;            // n*48 + m*8 + ps
  int n = b / 48;
  int r = b % 48;
  int m = r >> 3, ps = r & 7;
  int tid = threadIdx.x;
  if (tid < DD) {
    const float* src = Apart + ((size_t)(n * NCH + ps * 8) * 6 + m) * DD + tid;
    float s0 = src[0 * 6 * DD] + src[1 * 6 * DD];
    float s1 = src[2 * 6 * DD] + src[3 * 6 * DD];
    float s2 = src[4 * 6 * DD] + src[5 * 6 * DD];
    float s3 = src[6 * 6 * DD] + src[7 * 6 * DD];
    Ared8[((size_t)(n * PSPL + ps) * 6 + m) * DD + tid] = (s0 + s1) + (s2 + s3);
  } else if (m == 0 && tid >= 192 && tid < 204) {
    int k = tid - 192;
    const float* src = SWpart + (size_t)(n * NCH + ps * 8) * 12 + k;
    float s0 = src[0 * 12] + src[1 * 12];
    float s1 = src[2 * 12] + src[3 * 12];
    float s2 = src[4 * 12] + src[5 * 12];
    float s3 = src[6 * 12] + src[7 * 12];
    SWred8[(n * PSPL + ps) * 12 + k] = (s0 + s1) + (s2 + s3);
  }
}

// ---------------- k_slot3: per-(n,m) slot tail. grid = NN*MM, 256 threads ----------------
template <bool FIRST, bool LAST>
__global__ __launch_bounds__(256) void k_slot3(
    const float* __restrict__ slots_init, const float* __restrict__ Ared8,
    const float* __restrict__ SWred8, const float* __restrict__ Wv,
    const float* __restrict__ out_g, const float* __restrict__ out_b,
    const float* __restrict__ W1, const float* __restrict__ b1,
    const float* __restrict__ W2, const float* __restrict__ b2,
    const float* __restrict__ q_g, const float* __restrict__ q_b,
    const float* __restrict__ Wq, const float* __restrict__ Wk,
    const float* __restrict__ kv_g, const float* __restrict__ kv_b,
    const float* __restrict__ scal,
    float* __restrict__ slotbuf, float* __restrict__ P2, float* __restrict__ ab2,
    float* __restrict__ Sfin, float* __restrict__ out_slots) {
  int b = blockIdx.x;
  int n = b / MM, m = b % MM;
  int tid = threadIdx.x;
  __shared__ float a_s[DD];    // corrected-a row; later s2 (post-MLP slots)
  __shared__ float s1[DD];     // LN'd slots; later q-LN
  __shared__ float h[320];     // MLP hidden; later q
  __shared__ float pg[DD], pb[DD];
  __shared__ float sw_s[2];    // [0]=S(att sum), [1]=W(mu-weighted sum)
  __shared__ float Sv_s, mu_s, rs_s;

  // P0: SW reduce (16 threads: ps = tid&7, which = tid>>3)
  if (tid < 16) {
    int ps = tid & 7, which = tid >> 3;
    float v = SWred8[(size_t)(n * PSPL + ps) * 12 + m + 6 * which];
    v += __shfl_xor(v, 1); v += __shfl_xor(v, 2); v += __shfl_xor(v, 4);
    if (ps == 0) {
      if (which == 0) {
        sw_s[0] = v;
        float sc = fmaxf(v, 1e-6f);
        Sv_s = sc;
        if (LAST) Sfin[n * 6 + m] = sc;
      } else {
        sw_s[1] = v;
      }
    }
  }
  __syncthreads();
  // P1: a = g*(Araw - W) + b*S   (8-way coalesced Ared8 sum folded in)
  if (tid < DD) {
    const float* src = Ared8 + ((size_t)(n * PSPL) * 6 + m) * DD + tid;
    float ar = 0.f;
#pragma unroll
    for (int ps = 0; ps < PSPL; ps++) ar += src[(size_t)ps * 6 * DD];
    a_s[tid] = kv_g[tid] * (ar - sw_s[1]) + kv_b[tid] * sw_s[0];
  }
  __syncthreads();
  // P2: U = a @ Wv; slot update (pre-LN value into s1)
  if (tid < DD) {
    float u = 0.f;
#pragma unroll 8
    for (int c = 0; c < DD; c++) u = fmaf(a_s[c], Wv[c * DD + tid], u);
    float prev = FIRST ? slots_init[m * DD + tid] : slotbuf[(size_t)n * MM * DD + m * DD + tid];
    s1[tid] = prev + u / Sv_s;
  }
  __syncthreads();
  // P3: LN stats (wave 0)
  if (tid < 64) {
    float x0 = s1[tid], x1 = s1[tid + 64], x2 = (tid < 32) ? s1[tid + 128] : 0.f;
    float s = x0 + x1 + x2, ss = x0 * x0 + x1 * x1 + x2 * x2;
#pragma unroll
    for (int off = 32; off >= 1; off >>= 1) { s += __shfl_xor(s, off); ss += __shfl_xor(ss, off); }
    if (tid == 0) {
      float mu = s / DD, var = ss / DD - mu * mu;
      mu_s = mu; rs_s = rsqrtf(var + 1e-5f);
    }
  }
  __syncthreads();
  if (tid < DD) s1[tid] = (s1[tid] - mu_s) * rs_s * out_g[tid] + out_b[tid];
  __syncthreads();
  // P4: MLP hidden (320 outputs over 256 threads)
  for (int j = tid; j < 320; j += 256) {
    float acc = b1[j];
#pragma unroll 8
    for (int d = 0; d < DD; d++) acc = fmaf(s1[d], W1[d * 320 + j], acc);
    h[j] = 0.5f * acc * (1.0f + erff(acc * 0.70710678118f));
  }
  __syncthreads();
  // P5: MLP out + residual
  if (tid < DD) {
    float acc = b2[tid];
#pragma unroll 8
    for (int j = 0; j < 320; j++) acc = fmaf(h[j], W2[j * DD + tid], acc);
    float val = s1[tid] + acc;
    a_s[tid] = val;
    if (LAST) out_slots[(size_t)n * MM * DD + m * DD + tid] = val;
    else slotbuf[(size_t)n * MM * DD + m * DD + tid] = val;
  }
  if (!LAST) {
    __syncthreads();
    // P6: LN stats on s2
    if (tid < 64) {
      float x0 = a_s[tid], x1 = a_s[tid + 64], x2 = (tid < 32) ? a_s[tid + 128] : 0.f;
      float s = x0 + x1 + x2, ss = x0 * x0 + x1 * x1 + x2 * x2;
#pragma unroll
      for (int off = 32; off >= 1; off >>= 1) { s += __shfl_xor(s, off); ss += __shfl_xor(ss, off); }
      if (tid == 0) {
        float mu = s / DD, var = ss / DD - mu * mu;
        mu_s = mu; rs_s = rsqrtf(var + 1e-5f);
      }
    }
    __syncthreads();
    if (tid < DD) s1[tid] = (a_s[tid] - mu_s) * rs_s * q_g[tid] + q_b[tid];
    __syncthreads();
    // P7: q = ln @ Wq
    if (tid < DD) {
      float acc = 0.f;
#pragma unroll 8
      for (int i = 0; i < DD; i++) acc = fmaf(s1[i], Wq[i * DD + tid], acc);
      h[tid] = acc;
    }
    __syncthreads();
    // P8: Wkq column m: wr[c] = scal*(Wk[c,:].q); P2[c][m] = g*wr; pg/pb for ab2
    {
      int grp = tid >> 4, l = tid & 15;
      float sc = scal[0];
#pragma unroll 2
      for (int p = 0; p < 10; p++) {
        int c = p * 16 + grp;
        float s = 0.f;
#pragma unroll
        for (int i = 0; i < 10; i++) {
          int d = l + i * 16;
          s = fmaf(Wk[c * DD + d], h[d], s);
        }
        s += __shfl_xor(s, 1); s += __shfl_xor(s, 2);
        s += __shfl_xor(s, 4); s += __shfl_xor(s, 8);
        if (l == 0) {
          float wr = sc * s;
          float gv = kv_g[c] * wr;
          P2[(size_t)n * DD * 6 + c * 6 + m] = gv;
          pg[c] = gv;
          pb[c] = kv_b[c] * wr;
        }
      }
    }
    __syncthreads();
    // P9: ab2 = [sum pg | sum pb] via two wave reductions
    if (tid < 128) {
      int w = tid >> 6, l = tid & 63;
      const float* src = (w == 0) ? pg : pb;
      float x0 = src[l], x1 = src[l + 64], x2 = (l < 32) ? src[l + 128] : 0.f;
      float s = x0 + x1 + x2;
#pragma unroll
      for (int off = 32; off >= 1; off >>= 1) s += __shfl_xor(s, off);
      if (l == 0) ab2[n * 12 + 6 * w + m] = s;
    }
  }
}

// ---------------- k_norm: attn_map = attn / Sfin ----------------
__global__ __launch_bounds__(256) void k_norm(float* attn, const float* Sfin) {
  int idx = blockIdx.x * 256 + threadIdx.x;
  size_t base = (size_t)idx * 4;
  int nm = (int)(base >> 12);
  float s = Sfin[nm];
  float4 v = *(float4*)(attn + base);
  float inv = 1.0f / s;
  v.x *= inv; v.y *= inv; v.z *= inv; v.w *= inv;
  *(float4*)(attn + base) = v;
}

extern "C" void kernel_launch(void* const* d_in, const int* in_sizes, int n_in,
                              void* d_out, int out_size, void* d_ws, size_t ws_size,
                              hipStream_t stream) {
  const float* feat       = (const float*)d_in[0];
  const float* slots_init = (const float*)d_in[1];
  const float* log_tau    = (const float*)d_in[2];
  const float* kv_g       = (const float*)d_in[3];
  const float* kv_b       = (const float*)d_in[4];
  const float* Wk         = (const float*)d_in[5];
  const float* Wv         = (const float*)d_in[6];
  const float* q_g        = (const float*)d_in[7];
  const float* q_b        = (const float*)d_in[8];
  const float* Wq         = (const float*)d_in[9];
  const float* out_g      = (const float*)d_in[10];
  const float* out_b      = (const float*)d_in[11];
  const float* W1         = (const float*)d_in[12];
  const float* b1         = (const float*)d_in[13];
  const float* W2         = (const float*)d_in[14];
  const float* b2         = (const float*)d_in[15];
  float* out = (float*)d_out;
  float* out_attn = out + NN * MM * DD;

  // workspace (fp32, ~19 MB)
  float* Wkq1   = (float*)d_ws;                          // [160*6]
  float* ab     = Wkq1 + DD * 6;                         // [12] (pad 16)
  float* P1     = ab + 16;                               // [160*6]
  float* P2     = P1 + DD * 6;                           // [64][160*6]
  float* ab2    = P2 + (size_t)NN * DD * 6;              // [64][12]
  float* Apart  = ab2 + NN * 12;                         // [4096][6][160]
  float* SWpart = Apart + (size_t)NN * NCH * MM * DD;    // [4096][12]
  float* Ared8  = SWpart + (size_t)NN * NCH * 12;        // [64][8][6][160]
  float* SWred8 = Ared8 + (size_t)NN * PSPL * MM * DD;   // [64][8][12]
  float* Sfin   = SWred8 + NN * PSPL * 12;               // [64][6]
  float* scal   = Sfin + NN * MM;                        // [1] (pad 8)
  float* slotbuf = scal + 8;                             // [64][6][160]
  size_t required = (size_t)((char*)(slotbuf + NN * MM * DD) - (char*)d_ws);
  if (ws_size < required) return;

  k_init<<<16, 256, 0, stream>>>(log_tau, slots_init, q_g, q_b, Wq, Wk, Wkq1, scal);
  k_init2<<<1, 256, 0, stream>>>(Wkq1, kv_g, kv_b, P1, ab);
  k_pass<false><<<NN * NCH, 256, 0, stream>>>(feat, P1, ab, Apart, SWpart, out_attn);
  k_reduce<<<NN * MM * PSPL, 256, 0, stream>>>(Apart, SWpart, Ared8, SWred8);
  k_slot3<true, false><<<NN * MM, 256, 0, stream>>>(slots_init, Ared8, SWred8, Wv, out_g, out_b,
                                                    W1, b1, W2, b2, q_g, q_b, Wq, Wk, kv_g, kv_b, scal,
                                                    slotbuf, P2, ab2, Sfin, out);
  k_pass<true><<<NN * NCH, 256, 0, stream>>>(feat, P2, ab2, Apart, SWpart, out_attn);
  k_reduce<<<NN * MM * PSPL, 256, 0, stream>>>(Apart, SWpart, Ared8, SWred8);
  k_slot3<false, true><<<NN * MM, 256, 0, stream>>>(slots_init, Ared8, SWred8, Wv, out_g, out_b,
                                                    W1, b1, W2, b2, q_g, q_b, Wq, Wk, kv_g, kv_b, scal,
                                                    slotbuf, P2, ab2, Sfin, out);
  k_norm<<<(NN * MM * LL) / 1024, 256, 0, stream>>>(out_attn, Sfin);
}

// Round 17
// 213.952 us; speedup vs baseline: 3.5262x; 1.0459x over previous
//
#include <hip/hip_runtime.h>
#include <math.h>

#define NN 64
#define CC 160
#define LL 4096
#define DD 160
#define MM 6
#define NCH 16      // chunks per image; chunk = 256 tokens = 4 tiles of 64 (1024 blocks = 1 cohort)
#define NT 4
#define XSTR 68     // xb row stride in tokens (136B: b64 conflict-free)

#if defined(__has_builtin)
#if __has_builtin(__builtin_amdgcn_fdot2_f32_bf16)
#define HAVE_DOT2 1
#endif
#endif

__device__ __forceinline__ unsigned short f2bf(float f) {
  union { float f; unsigned int i; } v; v.f = f;
  unsigned int r = v.i + 0x7fffu + ((v.i >> 16) & 1u);
  return (unsigned short)(r >> 16);
}
__device__ __forceinline__ float u2f_lo(unsigned int w) {
  union { unsigned int i; float f; } v; v.i = w << 16; return v.f;
}
__device__ __forceinline__ float u2f_hi(unsigned int w) {
  union { unsigned int i; float f; } v; v.i = w & 0xffff0000u; return v.f;
}

#if HAVE_DOT2
typedef __bf16 v2bf __attribute__((ext_vector_type(2)));
__device__ __forceinline__ float dot2bf(unsigned int a, unsigned int b, float c) {
  union { unsigned int u; v2bf v; } ua, ub;
  ua.u = a; ub.u = b;
  return __builtin_amdgcn_fdot2_f32_bf16(ua.v, ub.v, c, false);
}
#else
__device__ __forceinline__ float dot2bf(unsigned int a, unsigned int b, float c) {
  return fmaf(u2f_hi(a), u2f_hi(b), fmaf(u2f_lo(a), u2f_lo(b), c));
}
#endif

// ---------------- k_init: scal = (d^-0.5 / tau); Wkq1 = scal * Wk @ q1^T ----------------
__global__ __launch_bounds__(256) void k_init(
    const float* log_tau, const float* slots_init, const float* q_g, const float* q_b,
    const float* Wq, const float* Wk, float* Wkq1, float* scal) {
  __shared__ float ln[MM * DD];
  __shared__ float qv[MM * DD];
  __shared__ float mu_s[MM], rs_s[MM];
  int tid = threadIdx.x;
  float x = log_tau[0];
  float sp = (x > 20.f) ? x : log1pf(expf(x));
  float scv = (1.0f / sqrtf((float)DD)) / (sp + 0.5f);
  if (blockIdx.x == 0 && tid == 0) scal[0] = scv;
  if (tid < MM) {
    float s = 0.f, ss = 0.f;
    for (int i = 0; i < DD; i++) { float v = slots_init[tid * DD + i]; s += v; ss += v * v; }
    float mu = s / DD, var = ss / DD - mu * mu;
    mu_s[tid] = mu; rs_s[tid] = rsqrtf(var + 1e-5f);
  }
  __syncthreads();
  for (int o = tid; o < MM * DD; o += 256) {
    int m = o / DD, d = o % DD;
    ln[o] = (slots_init[o] - mu_s[m]) * rs_s[m] * q_g[d] + q_b[d];
  }
  __syncthreads();
  for (int o = tid; o < MM * DD; o += 256) {
    int m = o / DD, d = o % DD;
    float acc = 0.f;
#pragma unroll 8
    for (int i = 0; i < DD; i++) acc += ln[m * DD + i] * Wq[i * DD + d];
    qv[o] = acc;
  }
  __syncthreads();
  for (int o = tid; o < 60; o += 256) {
    int c = blockIdx.x * 10 + o / 6, m = o % 6;
    float acc = 0.f;
#pragma unroll 8
    for (int d = 0; d < DD; d++) acc += Wk[c * DD + d] * qv[m * DD + d];
    Wkq1[c * 6 + m] = scv * acc;
  }
}

// ---------------- k_init2: P1 = g .* Wkq1; ab = [alpha | beta] ----------------
__global__ __launch_bounds__(256) void k_init2(
    const float* Wkq1, const float* kv_g, const float* kv_b, float* P1, float* ab) {
  int tid = threadIdx.x;
  for (int o = tid; o < DD * 6; o += 256) {
    int c = o / 6;
    P1[o] = kv_g[c] * Wkq1[o];
  }
  if (tid < 192) {
    int grp = tid >> 4;
    int l = tid & 15;
    int m = grp % 6;
    const float* coef = (grp < 6) ? kv_g : kv_b;
    float s = 0.f;
#pragma unroll
    for (int i = 0; i < 10; i++) {
      int c = l + i * 16;
      s += coef[c] * Wkq1[c * 6 + m];
    }
    s += __shfl_xor(s, 1); s += __shfl_xor(s, 2);
    s += __shfl_xor(s, 4); s += __shfl_xor(s, 8);
    if (l == 0) ab[grp] = s;
  }
}

// ---------------- k_pass: 4 tiles/block (cohort-resident); lean 3-barrier tile body ----------------
template <bool ITER2>
__global__ __launch_bounds__(256) void k_pass(
    const float* __restrict__ feat, const float* __restrict__ Pg,
    const float* __restrict__ abg, float* __restrict__ Apart,
    float* __restrict__ SWpart, float* __restrict__ attn_out) {
  int b = blockIdx.x;
  int n = b >> 4, ch = b & 15;
  int tid = threadIdx.x;
  int lane = tid & 63, g = tid >> 6;
  int cg = lane >> 4, tl = lane & 15;

  __shared__ __align__(16) unsigned short xb[160 * XSTR];
  __shared__ __align__(8) float part[4][16][4][10];
  __shared__ __align__(16) unsigned int w2_s[32][8];
  __shared__ __align__(16) float P_s[160][8];

  const float* wsrc = ITER2 ? (Pg + (size_t)n * DD * 6) : Pg;
  for (int o = tid; o < DD * 6; o += 256) P_s[o / 6][o % 6] = wsrc[o];
  const float* absrc = ITER2 ? (abg + n * 12) : abg;
  float alpha[6], beta[6];
#pragma unroll
  for (int m = 0; m < 6; m++) { alpha[m] = absrc[m]; beta[m] = absrc[6 + m]; }
  float Aacc[6] = {0, 0, 0, 0, 0, 0};   // tid<160: channel accumulator across tiles
  float Sacc[6] = {0, 0, 0, 0, 0, 0};   // g==2: att sums; g==3: w*mu sums
  __syncthreads();

  const float* fb0 = feat + ((size_t)(n * CC + g * 40 + cg)) * LL + ch * (64 * NT) + 4 * tl;

#pragma unroll 1
  for (int t4 = 0; t4 < NT; t4++) {
    const float* fb = fb0 + t4 * 64;
    // ---- phase 0: float4 load; fused stats + logit partials; bf16 raw-x to LDS ----
    float s4[4] = {0, 0, 0, 0}, ss4[4] = {0, 0, 0, 0};
    float lgr[6][4];
#pragma unroll
    for (int m = 0; m < 6; m++) { lgr[m][0] = 0.f; lgr[m][1] = 0.f; lgr[m][2] = 0.f; lgr[m][3] = 0.f; }
#pragma unroll
    for (int r = 0; r < 10; r++) {
      int c = g * 40 + r * 4 + cg;
      float4 xv = *(const float4*)(fb + (size_t)(r * 4) * LL);
      float4 p03 = *(const float4*)&P_s[c][0];
      float2 p45 = *(const float2*)&P_s[c][4];
      float xs[4] = {xv.x, xv.y, xv.z, xv.w};
#pragma unroll
      for (int j = 0; j < 4; j++) {
        float x = xs[j];
        s4[j] += x; ss4[j] = fmaf(x, x, ss4[j]);
        lgr[0][j] = fmaf(x, p03.x, lgr[0][j]); lgr[1][j] = fmaf(x, p03.y, lgr[1][j]);
        lgr[2][j] = fmaf(x, p03.z, lgr[2][j]); lgr[3][j] = fmaf(x, p03.w, lgr[3][j]);
        lgr[4][j] = fmaf(x, p45.x, lgr[4][j]); lgr[5][j] = fmaf(x, p45.y, lgr[5][j]);
      }
      uint2 pk;
      pk.x = (unsigned int)f2bf(xv.x) | ((unsigned int)f2bf(xv.y) << 16);
      pk.y = (unsigned int)f2bf(xv.z) | ((unsigned int)f2bf(xv.w) << 16);
      *(uint2*)&xb[c * XSTR + 4 * tl] = pk;
    }
#pragma unroll
    for (int j = 0; j < 4; j++) {
      s4[j] += __shfl_xor(s4[j], 16);  s4[j] += __shfl_xor(s4[j], 32);
      ss4[j] += __shfl_xor(ss4[j], 16); ss4[j] += __shfl_xor(ss4[j], 32);
#pragma unroll
      for (int m = 0; m < 6; m++) {
        lgr[m][j] += __shfl_xor(lgr[m][j], 16);
        lgr[m][j] += __shfl_xor(lgr[m][j], 32);
      }
    }
    if (cg == 0) {
#pragma unroll
      for (int j = 0; j < 4; j++) {
        float* pp = &part[g][tl][j][0];
        *(float2*)&pp[0] = make_float2(s4[j], ss4[j]);
        *(float2*)&pp[2] = make_float2(lgr[0][j], lgr[1][j]);
        *(float2*)&pp[4] = make_float2(lgr[2][j], lgr[3][j]);
        *(float2*)&pp[6] = make_float2(lgr[4][j], lgr[5][j]);
      }
    }
    __syncthreads();

    // ---- phase 1: all-wave combine+softmax; wave-role outputs ----
    {
      int tg = lane >> 2, tj = lane & 3;
      float S = 0.f, SS = 0.f, L[6] = {0, 0, 0, 0, 0, 0};
#pragma unroll
      for (int g2 = 0; g2 < 4; g2++) {
        const float* pp = &part[g2][tg][tj][0];
        float2 a = *(const float2*)&pp[0];
        float2 b2_ = *(const float2*)&pp[2];
        float2 c2 = *(const float2*)&pp[4];
        float2 d2 = *(const float2*)&pp[6];
        S += a.x; SS += a.y;
        L[0] += b2_.x; L[1] += b2_.y; L[2] += c2.x; L[3] += c2.y; L[4] += d2.x; L[5] += d2.y;
      }
      float mu = S * (1.0f / CC);
      float var = SS * (1.0f / CC) - mu * mu;
      float rs = rsqrtf(var + 1e-5f);
      float lg[6];
#pragma unroll
      for (int m = 0; m < 6; m++) lg[m] = rs * L[m] - rs * mu * alpha[m] + beta[m];
      float mx = lg[0];
#pragma unroll
      for (int m = 1; m < 6; m++) mx = fmaxf(mx, lg[m]);
      float e[6], sum = 0.f;
#pragma unroll
      for (int m = 0; m < 6; m++) { e[m] = __expf(lg[m] - mx); sum += e[m]; }
      float inv = 1.0f / sum;
      float att[6], wv[6];
#pragma unroll
      for (int m = 0; m < 6; m++) { att[m] = e[m] * inv; wv[m] = att[m] * rs; }

      if (g == 0) {
        float wo[6];
#pragma unroll
        for (int m = 0; m < 6; m++) wo[m] = __shfl_xor(wv[m], 1);
        if (!(lane & 1)) {
          int tp = lane >> 1;
          unsigned int pk[6];
#pragma unroll
          for (int m = 0; m < 6; m++) pk[m] = (unsigned int)f2bf(wv[m]) | ((unsigned int)f2bf(wo[m]) << 16);
          *(uint4*)&w2_s[tp][0] = make_uint4(pk[0], pk[1], pk[2], pk[3]);
          *(uint2*)&w2_s[tp][4] = make_uint2(pk[4], pk[5]);
        }
      } else if (g == 1) {
        if (ITER2) {
          size_t ob = ((size_t)(n * MM)) * LL + ch * (64 * NT) + t4 * 64 + lane;
#pragma unroll
          for (int m = 0; m < 6; m++) attn_out[ob + (size_t)m * LL] = att[m];
        }
      } else if (g == 2) {
#pragma unroll
        for (int m = 0; m < 6; m++) Sacc[m] += att[m];
      } else {
#pragma unroll
        for (int m = 0; m < 6; m++) Sacc[m] += wv[m] * mu;
      }
    }
    __syncthreads();

    // ---- phase 2: A accumulation via bf16 dot2 (tid<160 = channel c) ----
    if (tid < DD) {
      const unsigned short* xr = &xb[tid * XSTR];
#pragma unroll
      for (int k = 0; k < 16; k++) {
        uint2 xw = *(const uint2*)(xr + 4 * k);
        uint4 wa0 = *(const uint4*)&w2_s[2 * k][0];
        uint2 wb0 = *(const uint2*)&w2_s[2 * k][4];
        uint4 wa1 = *(const uint4*)&w2_s[2 * k + 1][0];
        uint2 wb1 = *(const uint2*)&w2_s[2 * k + 1][4];
        Aacc[0] = dot2bf(wa0.x, xw.x, Aacc[0]); Aacc[1] = dot2bf(wa0.y, xw.x, Aacc[1]);
        Aacc[2] = dot2bf(wa0.z, xw.x, Aacc[2]); Aacc[3] = dot2bf(wa0.w, xw.x, Aacc[3]);
        Aacc[4] = dot2bf(wb0.x, xw.x, Aacc[4]); Aacc[5] = dot2bf(wb0.y, xw.x, Aacc[5]);
        Aacc[0] = dot2bf(wa1.x, xw.y, Aacc[0]); Aacc[1] = dot2bf(wa1.y, xw.y, Aacc[1]);
        Aacc[2] = dot2bf(wa1.z, xw.y, Aacc[2]); Aacc[3] = dot2bf(wa1.w, xw.y, Aacc[3]);
        Aacc[4] = dot2bf(wb1.x, xw.y, Aacc[4]); Aacc[5] = dot2bf(wb1.y, xw.y, Aacc[5]);
      }
    }
    __syncthreads();
  }

  // ---- finals ----
  if (g == 2 || g == 3) {
#pragma unroll
    for (int m = 0; m < 6; m++) {
      float v = Sacc[m];
      v += __shfl_xor(v, 1);  v += __shfl_xor(v, 2);  v += __shfl_xor(v, 4);
      v += __shfl_xor(v, 8);  v += __shfl_xor(v, 16); v += __shfl_xor(v, 32);
      if (lane == 0) SWpart[b * 12 + (g - 2) * 6 + m] = v;
    }
  }
  if (tid < DD) {
#pragma unroll
    for (int m = 0; m < 6; m++) Apart[((size_t)b * 6 + m) * DD + tid] = Aacc[m];
  }
}

// ---------------- k_slot3: per-(n,m) slot tail. grid = NN*MM, 256 threads ----------------
template <bool FIRST, bool LAST>
__global__ __launch_bounds__(256) void k_slot3(
    const float* __restrict__ slots_init, const float* __restrict__ Apart,
    const float* __restrict__ SWpart, const float* __restrict__ Wv,
    const float* __restrict__ out_g, const float* __restrict__ out_b,
    const float* __restrict__ W1, const float* __restrict__ b1,
    const float* __restrict__ W2, const float* __restrict__ b2,
    const float* __restrict__ q_g, const float* __restrict__ q_b,
    const float* __restrict__ Wq, const float* __restrict__ Wk,
    const float* __restrict__ kv_g, const float* __restrict__ kv_b,
    const float* __restrict__ scal,
    float* __restrict__ slotbuf, float* __restrict__ P2, float* __restrict__ ab2,
    float* __restrict__ Sfin, float* __restrict__ out_slots) {
  int b = blockIdx.x;
  int n = b / MM, m = b % MM;
  int tid = threadIdx.x;
  __shared__ float a_s[DD];
  __shared__ float s1[DD];
  __shared__ float h[320];
  __shared__ float pg[DD], pb[DD];
  __shared__ float sw_s[2];
  __shared__ float Sv_s, mu_s, rs_s;

  // P0: SW reduce over 16 chunks (32 threads: p = tid&15, which = tid>>4)
  if (tid < 32) {
    int p = tid & 15, which = tid >> 4;
    float v = SWpart[(size_t)(n * NCH + p) * 12 + m + 6 * which];
    v += __shfl_xor(v, 1); v += __shfl_xor(v, 2);
    v += __shfl_xor(v, 4); v += __shfl_xor(v, 8);
    if (p == 0) {
      sw_s[which] = v;
      if (which == 0) {
        float sc = fmaxf(v, 1e-6f);
        Sv_s = sc;
        if (LAST) Sfin[n * 6 + m] = sc;
      }
    }
  }
  __syncthreads();
  // P1: a = g*(Araw - W) + b*S  (16-way coalesced Apart sum folded in)
  if (tid < DD) {
    const float* src = Apart + ((size_t)(n * NCH) * 6 + m) * DD + tid;
    float ar = 0.f;
#pragma unroll
    for (int p = 0; p < NCH; p++) ar += src[(size_t)p * 6 * DD];
    a_s[tid] = kv_g[tid] * (ar - sw_s[1]) + kv_b[tid] * sw_s[0];
  }
  __syncthreads();
  // P2: U = a @ Wv; slot update
  if (tid < DD) {
    float u = 0.f;
#pragma unroll 8
    for (int c = 0; c < DD; c++) u = fmaf(a_s[c], Wv[c * DD + tid], u);
    float prev = FIRST ? slots_init[m * DD + tid] : slotbuf[(size_t)n * MM * DD + m * DD + tid];
    s1[tid] = prev + u / Sv_s;
  }
  __syncthreads();
  // P3: LN
  if (tid < 64) {
    float x0 = s1[tid], x1 = s1[tid + 64], x2 = (tid < 32) ? s1[tid + 128] : 0.f;
    float s = x0 + x1 + x2, ss = x0 * x0 + x1 * x1 + x2 * x2;
#pragma unroll
    for (int off = 32; off >= 1; off >>= 1) { s += __shfl_xor(s, off); ss += __shfl_xor(ss, off); }
    if (tid == 0) {
      float mu = s / DD, var = ss / DD - mu * mu;
      mu_s = mu; rs_s = rsqrtf(var + 1e-5f);
    }
  }
  __syncthreads();
  if (tid < DD) s1[tid] = (s1[tid] - mu_s) * rs_s * out_g[tid] + out_b[tid];
  __syncthreads();
  // P4: MLP hidden
  for (int j = tid; j < 320; j += 256) {
    float acc = b1[j];
#pragma unroll 8
    for (int d = 0; d < DD; d++) acc = fmaf(s1[d], W1[d * 320 + j], acc);
    h[j] = 0.5f * acc * (1.0f + erff(acc * 0.70710678118f));
  }
  __syncthreads();
  // P5: MLP out + residual
  if (tid < DD) {
    float acc = b2[tid];
#pragma unroll 8
    for (int j = 0; j < 320; j++) acc = fmaf(h[j], W2[j * DD + tid], acc);
    float val = s1[tid] + acc;
    a_s[tid] = val;
    if (LAST) out_slots[(size_t)n * MM * DD + m * DD + tid] = val;
    else slotbuf[(size_t)n * MM * DD + m * DD + tid] = val;
  }
  if (!LAST) {
    __syncthreads();
    // P6: q-LN stats
    if (tid < 64) {
      float x0 = a_s[tid], x1 = a_s[tid + 64], x2 = (tid < 32) ? a_s[tid + 128] : 0.f;
      float s = x0 + x1 + x2, ss = x0 * x0 + x1 * x1 + x2 * x2;
#pragma unroll
      for (int off = 32; off >= 1; off >>= 1) { s += __shfl_xor(s, off); ss += __shfl_xor(ss, off); }
      if (tid == 0) {
        float mu = s / DD, var = ss / DD - mu * mu;
        mu_s = mu; rs_s = rsqrtf(var + 1e-5f);
      }
    }
    __syncthreads();
    if (tid < DD) s1[tid] = (a_s[tid] - mu_s) * rs_s * q_g[tid] + q_b[tid];
    __syncthreads();
    // P7: q = ln @ Wq
    if (tid < DD) {
      float acc = 0.f;
#pragma unroll 8
      for (int i = 0; i < DD; i++) acc = fmaf(s1[i], Wq[i * DD + tid], acc);
      h[tid] = acc;
    }
    __syncthreads();
    // P8: Wkq column m
    {
      int grp = tid >> 4, l = tid & 15;
      float sc = scal[0];
#pragma unroll 2
      for (int p = 0; p < 10; p++) {
        int c = p * 16 + grp;
        float s = 0.f;
#pragma unroll
        for (int i = 0; i < 10; i++) {
          int d = l + i * 16;
          s = fmaf(Wk[c * DD + d], h[d], s);
        }
        s += __shfl_xor(s, 1); s += __shfl_xor(s, 2);
        s += __shfl_xor(s, 4); s += __shfl_xor(s, 8);
        if (l == 0) {
          float wr = sc * s;
          float gv = kv_g[c] * wr;
          P2[(size_t)n * DD * 6 + c * 6 + m] = gv;
          pg[c] = gv;
          pb[c] = kv_b[c] * wr;
        }
      }
    }
    __syncthreads();
    // P9: ab2
    if (tid < 128) {
      int w = tid >> 6, l = tid & 63;
      const float* src = (w == 0) ? pg : pb;
      float x0 = src[l], x1 = src[l + 64], x2 = (l < 32) ? src[l + 128] : 0.f;
      float s = x0 + x1 + x2;
#pragma unroll
      for (int off = 32; off >= 1; off >>= 1) s += __shfl_xor(s, off);
      if (l == 0) ab2[n * 12 + 6 * w + m] = s;
    }
  }
}

// ---------------- k_norm: attn_map = attn / Sfin ----------------
__global__ __launch_bounds__(256) void k_norm(float* attn, const float* Sfin) {
  int idx = blockIdx.x * 256 + threadIdx.x;
  size_t base = (size_t)idx * 4;
  int nm = (int)(base >> 12);
  float s = Sfin[nm];
  float4 v = *(float4*)(attn + base);
  float inv = 1.0f / s;
  v.x *= inv; v.y *= inv; v.z *= inv; v.w *= inv;
  *(float4*)(attn + base) = v;
}

extern "C" void kernel_launch(void* const* d_in, const int* in_sizes, int n_in,
                              void* d_out, int out_size, void* d_ws, size_t ws_size,
                              hipStream_t stream) {
  const float* feat       = (const float*)d_in[0];
  const float* slots_init = (const float*)d_in[1];
  const float* log_tau    = (const float*)d_in[2];
  const float* kv_g       = (const float*)d_in[3];
  const float* kv_b       = (const float*)d_in[4];
  const float* Wk         = (const float*)d_in[5];
  const float* Wv         = (const float*)d_in[6];
  const float* q_g        = (const float*)d_in[7];
  const float* q_b        = (const float*)d_in[8];
  const float* Wq         = (const float*)d_in[9];
  const float* out_g      = (const float*)d_in[10];
  const float* out_b      = (const float*)d_in[11];
  const float* W1         = (const float*)d_in[12];
  const float* b1         = (const float*)d_in[13];
  const float* W2         = (const float*)d_in[14];
  const float* b2         = (const float*)d_in[15];
  float* out = (float*)d_out;
  float* out_attn = out + NN * MM * DD;

  // workspace (fp32, ~5 MB)
  float* Wkq1   = (float*)d_ws;                          // [160*6]
  float* ab     = Wkq1 + DD * 6;                         // [12] (pad 16)
  float* P1     = ab + 16;                               // [160*6]
  float* P2     = P1 + DD * 6;                           // [64][160*6]
  float* ab2    = P2 + (size_t)NN * DD * 6;              // [64][12]
  float* Apart  = ab2 + NN * 12;                         // [1024][6][160]
  float* SWpart = Apart + (size_t)NN * NCH * MM * DD;    // [1024][12]
  float* Sfin   = SWpart + (size_t)NN * NCH * 12;        // [64][6]
  float* scal   = Sfin + NN * MM;                        // [1] (pad 8)
  float* slotbuf = scal + 8;                             // [64][6][160]
  size_t required = (size_t)((char*)(slotbuf + NN * MM * DD) - (char*)d_ws);
  if (ws_size < required) return;

  k_init<<<16, 256, 0, stream>>>(log_tau, slots_init, q_g, q_b, Wq, Wk, Wkq1, scal);
  k_init2<<<1, 256, 0, stream>>>(Wkq1, kv_g, kv_b, P1, ab);
  k_pass<false><<<NN * NCH, 256, 0, stream>>>(feat, P1, ab, Apart, SWpart, out_attn);
  k_slot3<true, false><<<NN * MM, 256, 0, stream>>>(slots_init, Apart, SWpart, Wv, out_g, out_b,
                                                    W1, b1, W2, b2, q_g, q_b, Wq, Wk, kv_g, kv_b, scal,
                                                    slotbuf, P2, ab2, Sfin, out);
  k_pass<true><<<NN * NCH, 256, 0, stream>>>(feat, P2, ab2, Apart, SWpart, out_attn);
  k_slot3<false, true><<<NN * MM, 256, 0, stream>>>(slots_init, Apart, SWpart, Wv, out_g, out_b,
                                                    W1, b1, W2, b2, q_g, q_b, Wq, Wk, kv_g, kv_b, scal,
                                                    slotbuf, P2, ab2, Sfin, out);
  k_norm<<<(NN * MM * LL) / 1024, 256, 0, stream>>>(out_attn, Sfin);
}